// Round 3
// baseline (965.647 us; speedup 1.0000x reference)
//
#include <hip/hip_runtime.h>

#define BN_EPS 1e-5f

// ---------------- degree / dinv ----------------

__global__ __launch_bounds__(256) void k_deg_count(const int* __restrict__ dst, int* deg, int e) {
    int i = blockIdx.x * 256 + threadIdx.x;
    if (i < e) atomicAdd(&deg[dst[i]], 1);
}

__global__ __launch_bounds__(256) void k_dinv(const int* __restrict__ deg, float* __restrict__ dinv, int n) {
    int i = blockIdx.x * 256 + threadIdx.x;
    if (i < n) dinv[i] = rsqrtf((float)deg[i] + 1.0f);   // +1 = self-loop
}

// ---------------- exclusive scan (CSR offsets) ----------------

__global__ __launch_bounds__(256) void k_scan1(const int* __restrict__ deg, int* __restrict__ off,
                                               int* __restrict__ bsum, int n) {
    __shared__ int sh[256];
    int i = blockIdx.x * 256 + threadIdx.x;
    int v = (i < n) ? deg[i] : 0;
    sh[threadIdx.x] = v;
    __syncthreads();
    #pragma unroll
    for (int d = 1; d < 256; d <<= 1) {
        int t = (threadIdx.x >= d) ? sh[threadIdx.x - d] : 0;
        __syncthreads();
        sh[threadIdx.x] += t;
        __syncthreads();
    }
    if (i < n) off[i] = sh[threadIdx.x] - v;
    if (threadIdx.x == 255) bsum[blockIdx.x] = sh[255];
}

__global__ __launch_bounds__(512) void k_scan2(int* bsum, int nb) {
    __shared__ int sh[512];
    int v = (threadIdx.x < nb) ? bsum[threadIdx.x] : 0;
    sh[threadIdx.x] = v;
    __syncthreads();
    #pragma unroll
    for (int d = 1; d < 512; d <<= 1) {
        int t = (threadIdx.x >= d) ? sh[threadIdx.x - d] : 0;
        __syncthreads();
        sh[threadIdx.x] += t;
        __syncthreads();
    }
    if (threadIdx.x < nb) bsum[threadIdx.x] = sh[threadIdx.x] - v;
}

__global__ __launch_bounds__(256) void k_scan3(int* __restrict__ off, const int* __restrict__ bsum,
                                               int* __restrict__ cnt, int n, int e) {
    int i = blockIdx.x * 256 + threadIdx.x;
    if (i < n) { off[i] += bsum[blockIdx.x]; cnt[i] = 0; }
    if (i == 0) off[n] = e;
}

__global__ __launch_bounds__(256) void k_fill(const int* __restrict__ src, const int* __restrict__ dst,
                                              const int* __restrict__ off, int* __restrict__ cnt,
                                              int* __restrict__ esrc, int e) {
    int i = blockIdx.x * 256 + threadIdx.x;
    if (i < e) {
        int d = dst[i];
        int slot = off[d] + atomicAdd(&cnt[d], 1);
        esrc[slot] = src[i];
    }
}

// ---------------- dense linear: W in VGPRs, X staged in LDS, float4 broadcast reads ----
// block = 256 = 4 waves. Lane holds output column col = lane % FOUT and FIN weight regs.
// Wave processes RPW = 4*(64/FOUT) rows per iteration (4 accumulators per lane).

template<int FIN, int FOUT, bool RELU, bool BIAS, bool BNIN, bool DSCALE>
__global__ __launch_bounds__(256) void k_linear(const float* __restrict__ X, const float* __restrict__ W,
                                                const float* __restrict__ bias, float* __restrict__ Y,
                                                const float* __restrict__ S, const float* __restrict__ bng,
                                                const float* __restrict__ bnb, const float* __restrict__ dinv,
                                                float inv_n, int n) {
    constexpr int RS  = 64 / FOUT;   // row-slots per wave
    constexpr int RPW = RS * 4;      // rows per wave per iteration
    constexpr int RB  = RPW * 4;     // rows per block per iteration
    constexpr int K4  = FIN / 4;
    __shared__ float Xs[RB][FIN + 4];
    __shared__ float scs[BNIN ? FIN : 4], sfs[BNIN ? FIN : 4];

    const int wv  = threadIdx.x >> 6;
    const int lane = threadIdx.x & 63;
    const int col = lane % FOUT;
    const int rs  = lane / FOUT;

    if (BNIN && threadIdx.x < FIN) {
        int c = threadIdx.x;
        float mu = S[c] * inv_n;
        float var = S[FIN + c] * inv_n - mu * mu;
        float is = rsqrtf(var + BN_EPS) * bng[c];
        scs[c] = is;
        sfs[c] = bnb[c] - mu * is;
    }

    float Wreg[FIN];
    #pragma unroll
    for (int k = 0; k < FIN; ++k) Wreg[k] = W[k * FOUT + col];
    const float bcol = BIAS ? bias[col] : 0.0f;

    for (int r0 = blockIdx.x * RB; r0 < n; r0 += gridDim.x * RB) {
        __syncthreads();
        for (int idx = threadIdx.x; idx < RB * K4; idx += 256) {
            int rr = idx / K4, k4 = idx % K4;
            int row = r0 + rr;
            float4 v = make_float4(0.f, 0.f, 0.f, 0.f);
            if (row < n) v = *(const float4*)(X + (size_t)row * FIN + 4 * k4);
            if (BNIN) {
                v.x = fmaxf(fmaf(v.x, scs[4*k4+0], sfs[4*k4+0]), 0.f);
                v.y = fmaxf(fmaf(v.y, scs[4*k4+1], sfs[4*k4+1]), 0.f);
                v.z = fmaxf(fmaf(v.z, scs[4*k4+2], sfs[4*k4+2]), 0.f);
                v.w = fmaxf(fmaf(v.w, scs[4*k4+3], sfs[4*k4+3]), 0.f);
            }
            *(float4*)(&Xs[rr][4 * k4]) = v;
        }
        __syncthreads();
        float acc[4] = { bcol, bcol, bcol, bcol };
        #pragma unroll
        for (int k4 = 0; k4 < K4; ++k4) {
            #pragma unroll
            for (int q = 0; q < 4; ++q) {
                int rl = wv * RPW + q * RS + rs;
                float4 xv = *(const float4*)(&Xs[rl][4 * k4]);
                acc[q] = fmaf(xv.x, Wreg[4*k4+0], acc[q]);
                acc[q] = fmaf(xv.y, Wreg[4*k4+1], acc[q]);
                acc[q] = fmaf(xv.z, Wreg[4*k4+2], acc[q]);
                acc[q] = fmaf(xv.w, Wreg[4*k4+3], acc[q]);
            }
        }
        #pragma unroll
        for (int q = 0; q < 4; ++q) {
            int row = r0 + wv * RPW + q * RS + rs;
            if (row < n) {
                float v = acc[q];
                if (RELU) v = fmaxf(v, 0.f);
                if (DSCALE) v *= dinv[row];
                Y[(size_t)row * FOUT + col] = v;
            }
        }
    }
}

// ---------------- GCN accumulate (CSR gather), T pre-scaled by dinv[row] ----------------
// Z[d,:] = dinv[d] * ( T[d,:] + sum_{s in N(d)} T[s,:] ) + bias ; + BN partial stats

__global__ __launch_bounds__(256) void k_accum64(const float* __restrict__ T, const int* __restrict__ esrc,
                                                 const int* __restrict__ off, const float* __restrict__ dinv,
                                                 const float* __restrict__ bias, float* __restrict__ Z,
                                                 float* __restrict__ S, int n) {
    const int lane = threadIdx.x & 63;
    const int wid = threadIdx.x >> 6;
    float s1 = 0.f, s2 = 0.f;
    const float bcol = bias[lane];
    for (int d = blockIdx.x * 4 + wid; d < n; d += gridDim.x * 4) {
        int o0 = off[d], o1 = off[d + 1];
        float dv = dinv[d];
        float acc = T[(size_t)d * 64 + lane];
        int o = o0;
        for (; o + 8 <= o1; o += 8) {
            int sa = esrc[o+0], sb = esrc[o+1], sc = esrc[o+2], sd = esrc[o+3];
            int se = esrc[o+4], sf = esrc[o+5], sg = esrc[o+6], sh = esrc[o+7];
            float va = T[(size_t)sa*64+lane], vb = T[(size_t)sb*64+lane];
            float vc = T[(size_t)sc*64+lane], vd = T[(size_t)sd*64+lane];
            float ve = T[(size_t)se*64+lane], vf = T[(size_t)sf*64+lane];
            float vg = T[(size_t)sg*64+lane], vh = T[(size_t)sh*64+lane];
            acc += ((va + vb) + (vc + vd)) + ((ve + vf) + (vg + vh));
        }
        for (; o + 2 <= o1; o += 2) {
            int sa = esrc[o], sb = esrc[o+1];
            acc += T[(size_t)sa*64+lane] + T[(size_t)sb*64+lane];
        }
        if (o < o1) acc += T[(size_t)esrc[o]*64+lane];
        float z = fmaf(acc, dv, bcol);
        Z[(size_t)d * 64 + lane] = z;
        s1 += z; s2 += z * z;
    }
    __shared__ float sh1[256], sh2[256];
    sh1[threadIdx.x] = s1;
    sh2[threadIdx.x] = s2;
    __syncthreads();
    if (wid == 0) {
        #pragma unroll
        for (int w = 1; w < 4; ++w) { s1 += sh1[w * 64 + lane]; s2 += sh2[w * 64 + lane]; }
        atomicAdd(&S[lane], s1);
        atomicAdd(&S[64 + lane], s2);
    }
}

// F == 16: one node per wave, 4 edges per iteration (lane = 4 edge-slots x 16 cols)
__global__ __launch_bounds__(256) void k_accum16(const float* __restrict__ T, const int* __restrict__ esrc,
                                                 const int* __restrict__ off, const float* __restrict__ dinv,
                                                 const float* __restrict__ bias, float* __restrict__ Z,
                                                 float* __restrict__ S, int n) {
    const int lane = threadIdx.x & 63;
    const int wid = threadIdx.x >> 6;
    const int col = lane & 15;
    const int es  = lane >> 4;
    float s1 = 0.f, s2 = 0.f;
    const float bcol = bias[col];
    for (int d = blockIdx.x * 4 + wid; d < n; d += gridDim.x * 4) {
        int o0 = off[d], o1 = off[d + 1];
        float dv = dinv[d];
        float part = 0.f;
        for (int base = o0; base < o1; base += 4) {
            int oo = base + es;
            if (oo < o1) part += T[(size_t)esrc[oo] * 16 + col];
        }
        part += __shfl_xor(part, 16);
        part += __shfl_xor(part, 32);
        float acc = T[(size_t)d * 16 + col] + part;
        float z = fmaf(acc, dv, bcol);
        if (es == 0) {
            Z[(size_t)d * 16 + col] = z;
            s1 += z; s2 += z * z;
        }
    }
    __shared__ float sh1[256], sh2[256];
    sh1[threadIdx.x] = (es == 0) ? s1 : 0.f;
    sh2[threadIdx.x] = (es == 0) ? s2 : 0.f;
    __syncthreads();
    if (threadIdx.x < 16) {
        s1 = sh1[col]; s2 = sh2[col];
        #pragma unroll
        for (int r = 1; r < 16; ++r) { s1 += sh1[r * 16 + col]; s2 += sh2[r * 16 + col]; }
        atomicAdd(&S[col], s1);
        atomicAdd(&S[16 + col], s2);
    }
}

// ---------------- fc2 + log_softmax (fused BN+relu input) ----------------

__global__ __launch_bounds__(256) void k_fc2_lsm(const float* __restrict__ Hin, const float* __restrict__ W,
                                                 const float* __restrict__ bias, const float* __restrict__ S,
                                                 const float* __restrict__ bng, const float* __restrict__ bnb,
                                                 float inv_n, float* __restrict__ out, int n) {
    __shared__ float Ws[256];
    __shared__ float bs[16], sc[16], sf[16];
    Ws[threadIdx.x] = W[threadIdx.x];
    if (threadIdx.x < 16) {
        int c = threadIdx.x;
        bs[c] = bias[c];
        float mu = S[c] * inv_n;
        float var = S[16 + c] * inv_n - mu * mu;
        float is = rsqrtf(var + BN_EPS) * bng[c];
        sc[c] = is;
        sf[c] = bnb[c] - mu * is;
    }
    __syncthreads();
    for (int row = blockIdx.x * 256 + threadIdx.x; row < n; row += gridDim.x * 256) {
        float h[16];
        const float4* hp = (const float4*)(Hin + (size_t)row * 16);
        #pragma unroll
        for (int q = 0; q < 4; ++q) {
            float4 h4 = hp[q];
            h[q*4+0] = h4.x; h[q*4+1] = h4.y; h[q*4+2] = h4.z; h[q*4+3] = h4.w;
        }
        #pragma unroll
        for (int k = 0; k < 16; ++k) h[k] = fmaxf(fmaf(h[k], sc[k], sf[k]), 0.0f);
        float o[16];
        #pragma unroll
        for (int c = 0; c < 16; ++c) {
            float acc = bs[c];
            #pragma unroll
            for (int k = 0; k < 16; ++k) acc += h[k] * Ws[k * 16 + c];
            o[c] = acc;
        }
        float m = o[0];
        #pragma unroll
        for (int c = 1; c < 16; ++c) m = fmaxf(m, o[c]);
        float ssum = 0.f;
        #pragma unroll
        for (int c = 0; c < 16; ++c) ssum += expf(o[c] - m);
        float lse = m + logf(ssum);
        float4* op = (float4*)(out + (size_t)row * 16);
        #pragma unroll
        for (int q = 0; q < 4; ++q) {
            float4 w4;
            w4.x = o[q*4+0] - lse; w4.y = o[q*4+1] - lse;
            w4.z = o[q*4+2] - lse; w4.w = o[q*4+3] - lse;
            op[q] = w4;
        }
    }
}

// ---------------- launch ----------------

extern "C" void kernel_launch(void* const* d_in, const int* in_sizes, int n_in,
                              void* d_out, int out_size, void* d_ws, size_t ws_size,
                              hipStream_t stream) {
    const float* x      = (const float*)d_in[0];
    const int*   ei     = (const int*)d_in[1];
    const float* fc1_w  = (const float*)d_in[2];
    const float* fc1_b  = (const float*)d_in[3];
    const float* conv_w[3] = { (const float*)d_in[4],  (const float*)d_in[8],  (const float*)d_in[12] };
    const float* conv_b[3] = { (const float*)d_in[5],  (const float*)d_in[9],  (const float*)d_in[13] };
    const float* bn_g[3]   = { (const float*)d_in[6],  (const float*)d_in[10], (const float*)d_in[14] };
    const float* bn_b[3]   = { (const float*)d_in[7],  (const float*)d_in[11], (const float*)d_in[15] };
    const float* fc2_w  = (const float*)d_in[16];
    const float* fc2_b  = (const float*)d_in[17];

    const int n = in_sizes[0] / 128;
    const int e = in_sizes[1] / 2;
    const int* src = ei;
    const int* dst = ei + e;
    const float inv_n = 1.0f / (float)n;

    float* A    = (float*)d_ws;            // n*64
    float* B    = A + (size_t)n * 64;      // n*64
    float* dinv = B + (size_t)n * 64;      // n
    int*   deg  = (int*)(dinv + n);        // n  (doubles as cnt)
    int*   off  = deg + n;                 // n+1
    int*   esrc = off + n + 1;             // e
    float* stats = (float*)(esrc + e);     // 3*128
    int*   bsum = (int*)(stats + 384);     // <=512

    const int gN  = (n + 255) / 256;
    const int gE  = (e + 255) / 256;
    const int gLin = 2048;
    const int gAcc = 2048;

    float* st[3] = { stats, stats + 128, stats + 256 };

    // CSR build (shared by all 3 conv layers)
    hipMemsetAsync(deg, 0, (size_t)n * sizeof(int), stream);
    hipMemsetAsync(stats, 0, 384 * sizeof(float), stream);
    k_deg_count<<<gE, 256, 0, stream>>>(dst, deg, e);
    k_dinv<<<gN, 256, 0, stream>>>(deg, dinv, n);
    k_scan1<<<gN, 256, 0, stream>>>(deg, off, bsum, n);
    k_scan2<<<1, 512, 0, stream>>>(bsum, gN);
    k_scan3<<<gN, 256, 0, stream>>>(off, bsum, deg /*cnt*/, n, e);
    k_fill<<<gE, 256, 0, stream>>>(src, dst, off, deg /*cnt*/, esrc, e);

    // fc1 + relu : A = relu(x @ W1 + b1)
    k_linear<128, 64, true, true, false, false><<<gLin, 256, 0, stream>>>(
        x, fc1_w, fc1_b, A, nullptr, nullptr, nullptr, nullptr, 0.f, n);

    // conv0: B = (A @ W0) * dinv[row] ; A = gcn(B) (+bias, +stats0)
    k_linear<64, 64, false, false, false, true><<<gLin, 256, 0, stream>>>(
        A, conv_w[0], nullptr, B, nullptr, nullptr, nullptr, dinv, 0.f, n);
    k_accum64<<<gAcc, 256, 0, stream>>>(B, esrc, off, dinv, conv_b[0], A, st[0], n);

    // conv1: B = (bnrelu(A) @ W1) * dinv[row] ; A = gcn(B)
    k_linear<64, 64, false, false, true, true><<<gLin, 256, 0, stream>>>(
        A, conv_w[1], nullptr, B, st[0], bn_g[0], bn_b[0], dinv, inv_n, n);
    k_accum64<<<gAcc, 256, 0, stream>>>(B, esrc, off, dinv, conv_b[1], A, st[1], n);

    // conv2: B = (bnrelu(A) @ W2) * dinv[row] (64->16) ; A = gcn(B)
    k_linear<64, 16, false, false, true, true><<<gLin, 256, 0, stream>>>(
        A, conv_w[2], nullptr, B, st[1], bn_g[1], bn_b[1], dinv, inv_n, n);
    k_accum16<<<gAcc, 256, 0, stream>>>(B, esrc, off, dinv, conv_b[2], A, st[2], n);

    // fc2 + log_softmax (bn+relu fused on input) -> d_out
    k_fc2_lsm<<<gLin, 256, 0, stream>>>(A, fc2_w, fc2_b, st[2], bn_g[2], bn_b[2], inv_n, (float*)d_out, n);
}